// Round 18
// baseline (94.503 us; speedup 1.0000x reference)
//
#include <hip/hip_runtime.h>

#define S_LEN 2048
#define E_DIM 1024
#define NH 16
#define HD 64
#define NT (S_LEN / 64)
// (1/sqrt(64)) * log2(e): fold softmax scale into log2 domain (applied to Q pre-cvt)
#define SCALE_L2E 0.18033688011112042f

typedef __bf16 bf16;
typedef __attribute__((ext_vector_type(4))) bf16 bf16x4;
typedef __attribute__((ext_vector_type(8))) bf16 bf16x8;
typedef __attribute__((ext_vector_type(4))) float f32x4;
typedef unsigned long long u64;
typedef unsigned int u32;

#define MFMA(a, b, c) __builtin_amdgcn_mfma_f32_16x16x32_bf16((a), (b), (c), 0, 0, 0)

__device__ __forceinline__ bf16x8 cvt8(f32x4 a, f32x4 b) {
  bf16x8 r;
  r[0] = (bf16)a[0]; r[1] = (bf16)a[1]; r[2] = (bf16)a[2]; r[3] = (bf16)a[3];
  r[4] = (bf16)b[0]; r[5] = (bf16)b[1]; r[6] = (bf16)b[2]; r[7] = (bf16)b[3];
  return r;
}

__device__ __forceinline__ bf16x8 load_cvt_frag(const float* p) {
  f32x4 a = *(const f32x4*)(p);
  f32x4 b = *(const f32x4*)(p + 16);
  return cvt8(a, b);
}

// ---------------- K/V projection + fused mask bit-pack (validated R6-R17) ----------------
__global__ __launch_bounds__(256) void kvproj_k(
    const float* __restrict__ Kin, const float* __restrict__ Vin,
    const float* __restrict__ Wk, const float* __restrict__ bk,
    const float* __restrict__ Wv, const float* __restrict__ bv,
    const int* __restrict__ mask,
    bf16* __restrict__ KpF, bf16* __restrict__ VpF, u64* __restrict__ bits) {
  const int xcd = blockIdx.x & 7;
  const int idx = blockIdx.x >> 3;           // 0..127
  const int bh = xcd * 4 + (idx >> 5);       // 4 heads per XCD
  const int sblk = idx & 31;                 // S/64 = 32
  const int h = bh & (NH - 1);
  const int b = bh >> 4;
  const int lane = threadIdx.x & 63;
  const int wave = threadIdx.x >> 6;
  const int g = lane >> 4;
  const int c16 = lane & 15;
  const int sbase = sblk * 64 + wave * 16;
  const int srow = sbase + c16;

  const float* xk = Kin + ((size_t)b * S_LEN + srow) * E_DIM + h * HD;
  const float* xv = Vin + ((size_t)b * S_LEN + srow) * E_DIM + h * HD;
  bf16x8 xkf[2], xvf[2];
#pragma unroll
  for (int c = 0; c < 2; ++c) {
    xkf[c] = load_cvt_frag(xk + 32 * c + 4 * g);
    xvf[c] = load_cvt_frag(xv + 32 * c + 4 * g);
  }

  // Kp = Xk * Wk^T + bk
#pragma unroll
  for (int nt = 0; nt < 4; ++nt) {
    const float* wr = Wk + (16 * nt + c16) * HD + 4 * g;
    f32x4 acc = {0.f, 0.f, 0.f, 0.f};
    acc = MFMA(xkf[0], load_cvt_frag(wr), acc);
    acc = MFMA(xkf[1], load_cvt_frag(wr + 32), acc);
    const float bias = bk[16 * nt + c16];
    const size_t fidx = (((size_t)bh * 32 + sblk) * 4 + wave) * 2 + (nt >> 1);
    const int e = (c16 & 3) + 4 * (nt & 1);
#pragma unroll
    for (int r = 0; r < 4; ++r) {
      const int lane_p = (c16 >> 2) * 16 + 4 * g + r;
      KpF[fidx * 512 + lane_p * 8 + e] = (bf16)(acc[r] + bias);
    }
  }
  // Vp (transposed): A = Wv rows=d_out, B = Xv^T
#pragma unroll
  for (int nt = 0; nt < 4; ++nt) {
    const float* wr = Wv + (16 * nt + c16) * HD + 4 * g;
    f32x4 acc = {0.f, 0.f, 0.f, 0.f};
    acc = MFMA(load_cvt_frag(wr), xvf[0], acc);
    acc = MFMA(load_cvt_frag(wr + 32), xvf[1], acc);
    const size_t fidx = (((size_t)bh * 32 + sblk) * 4 + nt) * 2 + (wave >> 1);
    const int e = (c16 & 3) + 4 * (wave & 1);
#pragma unroll
    for (int r = 0; r < 4; ++r) {
      const int dout = 16 * nt + 4 * g + r;
      const int lane_p = (c16 >> 2) * 16 + 4 * g + r;
      VpF[fidx * 512 + lane_p * 8 + e] = (bf16)(acc[r] + bv[dout]);
    }
  }

  // fused mask bit-pack: this block handles 64 words, 16 per wave
  const int wbase = blockIdx.x * 64 + wave * 16;
  int mv[16];
#pragma unroll
  for (int i = 0; i < 16; ++i) mv[i] = mask[(size_t)(wbase + i) * 64 + lane];
#pragma unroll
  for (int i = 0; i < 16; ++i) {
    const u64 bb = __ballot(mv[i] != 0);
    const int w = wbase + i;  // w = row*32 + colblk
    if (lane == 0) bits[(size_t)(w & 31) * S_LEN + (w >> 5)] = bb;
  }
}

// ---- attention: 4 waves x 32 q-rows (2 indep groups/wave), K+V LDS 2-buffer ----
// Every K/V fragment read feeds TWO q-groups (2x arithmetic intensity vs R16);
// group-1's QK MFMAs overlap group-0's elementwise softmax in-wave (max-free
// => no cross-lane serial sections). Counted vmcnt(2) keeps staging in flight.
__global__ __launch_bounds__(256) void attn_k(
    const float* __restrict__ Qin, const float* __restrict__ Wq, const float* __restrict__ bq,
    const bf16* __restrict__ KpF, const bf16* __restrict__ VpF,
    const u64* __restrict__ mbits, float* __restrict__ out) {
  const int xcd = blockIdx.x & 7;
  const int idx = blockIdx.x >> 3;       // 0..63
  const int bh = xcd * 4 + (idx >> 4);   // 4 heads per XCD
  const int qc = idx & 15;               // 128-row chunk
  const int h = bh & (NH - 1);
  const int b = bh >> 4;
  const int lane = threadIdx.x & 63;
  const int wave = threadIdx.x >> 6;     // 0..3
  const int g = lane >> 4;
  const int c16 = lane & 15;
  const int qbase = qc * 128 + wave * 32;   // this wave's 32 q-rows

  // 2 buffers x (8 K-frags | 8 V-frags) x 1KB = 32 KB
  __shared__ __align__(16) bf16 lds_kv[2][16 * 512];

  // Q projection in-register for both 16-row groups; scale folded pre-cvt.
  bf16x8 qfrag[2][2];
#pragma unroll
  for (int grp = 0; grp < 2; ++grp) {
    const int qrow = qbase + grp * 16 + c16;
    const float* xq = Qin + ((size_t)b * S_LEN + qrow) * E_DIM + h * HD;
    bf16x8 xqf[2];
#pragma unroll
    for (int c = 0; c < 2; ++c) xqf[c] = load_cvt_frag(xq + 32 * c + 4 * g);
    f32x4 qt[4];
#pragma unroll
    for (int t = 0; t < 4; ++t) {
      const float* wr = Wq + (16 * t + c16) * HD + 4 * g;
      f32x4 acc = {0.f, 0.f, 0.f, 0.f};
      acc = MFMA(load_cvt_frag(wr), xqf[0], acc);
      acc = MFMA(load_cvt_frag(wr + 32), xqf[1], acc);
#pragma unroll
      for (int r = 0; r < 4; ++r) acc[r] = (acc[r] + bq[16 * t + 4 * g + r]) * SCALE_L2E;
      qt[t] = acc;
    }
    qfrag[grp][0] = cvt8(qt[0], qt[1]);
    qfrag[grp][1] = cvt8(qt[2], qt[3]);
  }

  bf16x8 ones;
#pragma unroll
  for (int i = 0; i < 8; ++i) ones[i] = (bf16)1.0f;

  const bf16* ktile = KpF + ((size_t)bh * 32) * 4096;  // + t*4096 + f*512
  const bf16* vtile = VpF + ((size_t)bh * 32) * 4096;
  const u64* mrowT = mbits + qbase + c16;              // + t*S_LEN + grp*16

  f32x4 o[2][4] = {};
  f32x4 o5[2] = {};

  // wave w stages K frags {2w,2w+1} and V frags {2w,2w+1}: 4 loads/tile/wave
#define STAGE(BUF, T)                                                              \
  {                                                                                \
    const bf16* ks_ = ktile + (size_t)(T) * 4096 + (2 * wave) * 512 + lane * 8;    \
    const bf16* vs_ = vtile + (size_t)(T) * 4096 + (2 * wave) * 512 + lane * 8;    \
    __builtin_amdgcn_global_load_lds(                                              \
        (const __attribute__((address_space(1))) u32*)ks_,                         \
        (__attribute__((address_space(3))) u32*)((BUF) + (2 * wave) * 512), 16, 0, 0); \
    __builtin_amdgcn_global_load_lds(                                              \
        (const __attribute__((address_space(1))) u32*)(ks_ + 512),                 \
        (__attribute__((address_space(3))) u32*)((BUF) + (2 * wave + 1) * 512), 16, 0, 0); \
    __builtin_amdgcn_global_load_lds(                                              \
        (const __attribute__((address_space(1))) u32*)vs_,                         \
        (__attribute__((address_space(3))) u32*)((BUF) + 4096 + (2 * wave) * 512), 16, 0, 0); \
    __builtin_amdgcn_global_load_lds(                                              \
        (const __attribute__((address_space(1))) u32*)(vs_ + 512),                 \
        (__attribute__((address_space(3))) u32*)((BUF) + 4096 + (2 * wave + 1) * 512), 16, 0, 0); \
  }

  bf16* const B0 = &lds_kv[0][0];
  bf16* const B1 = &lds_kv[1][0];

  u64 mca[2], mcb[2];

  // prologue: stage tile 0 (4 loads), then masks (2 loads); vmcnt(2) retires stage
  STAGE(B0, 0)
  mca[0] = mrowT[0];
  mca[1] = mrowT[16];
  asm volatile("s_waitcnt vmcnt(2)" ::: "memory");
  asm volatile("s_barrier" ::: "memory");

  // ITER: [stage(t+1)->NXT (4)][masks(t+1) (2)][kf,vfr<-BUF][per-grp QK|softmax|PV][vmcnt(2)][barrier]
#define ITER(BUF, NXT, MWC, MWN, T)                                               \
  {                                                                               \
    const bool more_ = (T) + 1 < NT;                                              \
    if (more_) {                                                                  \
      STAGE(NXT, (T) + 1)                                                         \
      MWN[0] = mrowT[(size_t)((T) + 1) * S_LEN];                                  \
      MWN[1] = mrowT[(size_t)((T) + 1) * S_LEN + 16];                             \
    }                                                                             \
    const u64 mw0_ = MWC[0];                                                      \
    const u64 mw1_ = MWC[1];                                                      \
    bf16x8 kf[8], vfr[8];                                                         \
    _Pragma("unroll") for (int f = 0; f < 8; ++f)                                 \
        kf[f] = *(const bf16x8*)((BUF) + f * 512 + lane * 8);                     \
    _Pragma("unroll") for (int f = 0; f < 8; ++f)                                 \
        vfr[f] = *(const bf16x8*)((BUF) + 4096 + f * 512 + lane * 8);             \
    _Pragma("unroll") for (int grp = 0; grp < 2; ++grp) {                         \
      const u64 mws = ((grp == 0) ? mw0_ : mw1_) >> (4 * g);                      \
      const u32 mlo = (u32)mws;                                                   \
      const u32 mhi = (u32)(mws >> 32);                                           \
      f32x4 st[4];                                                                \
      __builtin_amdgcn_s_setprio(1);                                              \
      _Pragma("unroll") for (int ks = 0; ks < 4; ++ks) {                          \
        f32x4 acc = {0.f, 0.f, 0.f, 0.f};                                         \
        acc = MFMA(kf[2 * ks], qfrag[grp][0], acc);                               \
        acc = MFMA(kf[2 * ks + 1], qfrag[grp][1], acc);                           \
        st[ks] = acc;                                                             \
      }                                                                           \
      __builtin_amdgcn_s_setprio(0);                                              \
      _Pragma("unroll") for (int ks = 0; ks < 4; ++ks) {                          \
        const u32 mword = (ks < 2) ? mlo : mhi;                                   \
        const int base = (ks & 1) * 16;                                           \
        _Pragma("unroll") for (int r = 0; r < 4; ++r) {                           \
          const float p = __builtin_amdgcn_exp2f(st[ks][r]);                      \
          const int keep = __builtin_amdgcn_sbfe(mword, base + r, 1);             \
          st[ks][r] = __uint_as_float(__float_as_uint(p) & (u32)keep);            \
        }                                                                         \
      }                                                                           \
      const bf16x8 pfrag0 = cvt8(st[0], st[1]);                                   \
      const bf16x8 pfrag1 = cvt8(st[2], st[3]);                                   \
      __builtin_amdgcn_s_setprio(1);                                              \
      _Pragma("unroll") for (int t = 0; t < 4; ++t) {                             \
        o[grp][t] = MFMA(vfr[2 * t], pfrag0, o[grp][t]);                          \
        o[grp][t] = MFMA(vfr[2 * t + 1], pfrag1, o[grp][t]);                      \
      }                                                                           \
      o5[grp] = MFMA(ones, pfrag0, o5[grp]);                                      \
      o5[grp] = MFMA(ones, pfrag1, o5[grp]);                                      \
      __builtin_amdgcn_s_setprio(0);                                              \
    }                                                                             \
    if (more_) asm volatile("s_waitcnt vmcnt(2)" ::: "memory");                   \
    else       asm volatile("s_waitcnt vmcnt(0)" ::: "memory");                   \
    asm volatile("s_barrier" ::: "memory");                                       \
  }

  for (int t = 0; t < NT; t += 2) {
    ITER(B0, B1, mca, mcb, t)
    ITER(B1, B0, mcb, mca, t + 1)
  }
#undef ITER
#undef STAGE

#pragma unroll
  for (int grp = 0; grp < 2; ++grp) {
    const float inv = 1.0f / o5[grp][0];
    float* orow = out + ((size_t)b * S_LEN + qbase + grp * 16 + c16) * E_DIM + h * HD;
#pragma unroll
    for (int t = 0; t < 4; ++t) {
      f32x4 v;
#pragma unroll
      for (int r = 0; r < 4; ++r) v[r] = o[grp][t][r] * inv;
      *(f32x4*)(orow + 16 * t + 4 * g) = v;
    }
  }
}

extern "C" void kernel_launch(void* const* d_in, const int* in_sizes, int n_in,
                              void* d_out, int out_size, void* d_ws, size_t ws_size,
                              hipStream_t stream) {
  const float* Q = (const float*)d_in[0];
  const float* K = (const float*)d_in[1];
  const float* V = (const float*)d_in[2];
  const int* mask = (const int*)d_in[3];
  const float* Wq = (const float*)d_in[4];
  const float* bq = (const float*)d_in[5];
  const float* Wk = (const float*)d_in[6];
  const float* bk = (const float*)d_in[7];
  const float* Wv = (const float*)d_in[8];
  const float* bv = (const float*)d_in[9];
  float* out = (float*)d_out;

  char* ws = (char*)d_ws;
  const size_t proj_bytes = (size_t)2 * NH * S_LEN * HD * 2;  // 8 MB each (B=2)
  bf16* KpF = (bf16*)ws;
  bf16* VpF = (bf16*)(ws + proj_bytes);
  u64* mbits = (u64*)(ws + 2 * proj_bytes);      // 512 KB

  kvproj_k<<<2 * NH * (S_LEN / 64), 256, 0, stream>>>(K, V, Wk, bk, Wv, bv, mask,
                                                      KpF, VpF, mbits);
  // 512 blocks x 256 threads: 4 waves x 32 q-rows = 128 q-rows per block
  attn_k<<<2 * NH * (S_LEN / 128), 256, 0, stream>>>(Q, Wq, bq, KpF, VpF, mbits, out);
}

// Round 19
// 80.377 us; speedup vs baseline: 1.1757x; 1.1757x over previous
//
#include <hip/hip_runtime.h>

#define S_LEN 2048
#define E_DIM 1024
#define NH 16
#define HD 64
#define NT (S_LEN / 64)
// (1/sqrt(64)) * log2(e): fold softmax scale into log2 domain (applied to Q pre-cvt)
#define SCALE_L2E 0.18033688011112042f

typedef __bf16 bf16;
typedef __attribute__((ext_vector_type(4))) bf16 bf16x4;
typedef __attribute__((ext_vector_type(8))) bf16 bf16x8;
typedef __attribute__((ext_vector_type(4))) float f32x4;
typedef unsigned long long u64;
typedef unsigned int u32;

#define MFMA(a, b, c) __builtin_amdgcn_mfma_f32_16x16x32_bf16((a), (b), (c), 0, 0, 0)

__device__ __forceinline__ bf16x8 cvt8(f32x4 a, f32x4 b) {
  bf16x8 r;
  r[0] = (bf16)a[0]; r[1] = (bf16)a[1]; r[2] = (bf16)a[2]; r[3] = (bf16)a[3];
  r[4] = (bf16)b[0]; r[5] = (bf16)b[1]; r[6] = (bf16)b[2]; r[7] = (bf16)b[3];
  return r;
}

__device__ __forceinline__ bf16x8 load_cvt_frag(const float* p) {
  f32x4 a = *(const f32x4*)(p);
  f32x4 b = *(const f32x4*)(p + 16);
  return cvt8(a, b);
}

// ---------------- K/V projection + mask pack; LDS-bounce vectorized stores ----------------
__global__ __launch_bounds__(256) void kvproj_k(
    const float* __restrict__ Kin, const float* __restrict__ Vin,
    const float* __restrict__ Wk, const float* __restrict__ bk,
    const float* __restrict__ Wv, const float* __restrict__ bv,
    const int* __restrict__ mask,
    bf16* __restrict__ KpF, bf16* __restrict__ VpF, u64* __restrict__ bits) {
  const int xcd = blockIdx.x & 7;
  const int idx = blockIdx.x >> 3;           // 0..127
  const int bh = xcd * 4 + (idx >> 5);       // 4 heads per XCD
  const int sblk = idx & 31;                 // S/64 = 32
  const int h = bh & (NH - 1);
  const int b = bh >> 4;
  const int lane = threadIdx.x & 63;
  const int wave = threadIdx.x >> 6;
  const int g = lane >> 4;
  const int c16 = lane & 15;
  const int sbase = sblk * 64 + wave * 16;
  const int srow = sbase + c16;

  // bounce buffers: K frags are wave-private [wave][c]; V frags shared [nt*2+c]
  __shared__ __align__(16) bf16 lkb[4][2][512];
  __shared__ __align__(16) bf16 lvb[8][512];

  const float* xk = Kin + ((size_t)b * S_LEN + srow) * E_DIM + h * HD;
  const float* xv = Vin + ((size_t)b * S_LEN + srow) * E_DIM + h * HD;
  bf16x8 xkf[2], xvf[2];
#pragma unroll
  for (int c = 0; c < 2; ++c) {
    xkf[c] = load_cvt_frag(xk + 32 * c + 4 * g);
    xvf[c] = load_cvt_frag(xv + 32 * c + 4 * g);
  }

  // Kp = Xk * Wk^T + bk  -> bounce to LDS in fragment order
#pragma unroll
  for (int nt = 0; nt < 4; ++nt) {
    const float* wr = Wk + (16 * nt + c16) * HD + 4 * g;
    f32x4 acc = {0.f, 0.f, 0.f, 0.f};
    acc = MFMA(xkf[0], load_cvt_frag(wr), acc);
    acc = MFMA(xkf[1], load_cvt_frag(wr + 32), acc);
    const float bias = bk[16 * nt + c16];
    const int e = (c16 & 3) + 4 * (nt & 1);
#pragma unroll
    for (int r = 0; r < 4; ++r) {
      const int lane_p = (c16 >> 2) * 16 + 4 * g + r;
      lkb[wave][nt >> 1][lane_p * 8 + e] = (bf16)(acc[r] + bias);
    }
  }
  // Vp (transposed): A = Wv rows=d_out, B = Xv^T -> bounce to LDS
#pragma unroll
  for (int nt = 0; nt < 4; ++nt) {
    const float* wr = Wv + (16 * nt + c16) * HD + 4 * g;
    f32x4 acc = {0.f, 0.f, 0.f, 0.f};
    acc = MFMA(load_cvt_frag(wr), xvf[0], acc);
    acc = MFMA(load_cvt_frag(wr + 32), xvf[1], acc);
    const int e = (c16 & 3) + 4 * (wave & 1);
#pragma unroll
    for (int r = 0; r < 4; ++r) {
      const int dout = 16 * nt + 4 * g + r;
      const int lane_p = (c16 >> 2) * 16 + 4 * g + r;
      lvb[nt * 2 + (wave >> 1)][lane_p * 8 + e] = (bf16)(acc[r] + bv[dout]);
    }
  }
  __syncthreads();

  // vectorized readback + coalesced 16B stores
  const size_t base = ((size_t)bh * 32 + sblk) * 4;
#pragma unroll
  for (int c = 0; c < 2; ++c) {
    const bf16x8 v = *(const bf16x8*)&lkb[wave][c][lane * 8];
    *(bf16x8*)(KpF + ((base + wave) * 2 + c) * 512 + lane * 8) = v;
  }
#pragma unroll
  for (int i = 0; i < 2; ++i) {
    const int fi = 2 * wave + i;
    const bf16x8 v = *(const bf16x8*)&lvb[fi][lane * 8];
    *(bf16x8*)(VpF + ((base + (fi >> 1)) * 2 + (fi & 1)) * 512 + lane * 8) = v;
  }

  // fused mask bit-pack: this block handles 64 words, 16 per wave
  const int wbase = blockIdx.x * 64 + wave * 16;
  int mv[16];
#pragma unroll
  for (int i = 0; i < 16; ++i) mv[i] = mask[(size_t)(wbase + i) * 64 + lane];
#pragma unroll
  for (int i = 0; i < 16; ++i) {
    const u64 bb = __ballot(mv[i] != 0);
    const int w = wbase + i;  // w = row*32 + colblk
    if (lane == 0) bits[(size_t)(w & 31) * S_LEN + (w >> 5)] = bb;
  }
}

// ---- attention: 8 waves x 16 q-rows, 4-buffer LDS, ONE barrier per 2 tiles ----
// R16 body unchanged; phase = {stage t+2,t+3; compute t; compute t+1; vmcnt(2);
// barrier} -- halves the per-tile sync overhead (barrier + drain + phase-locked
// burst), which the R16 cycle audit identified as ~2x the pipe demand.
__global__ __launch_bounds__(512) void attn_k(
    const float* __restrict__ Qin, const float* __restrict__ Wq, const float* __restrict__ bq,
    const bf16* __restrict__ KpF, const bf16* __restrict__ VpF,
    const u64* __restrict__ mbits, float* __restrict__ out) {
  const int xcd = blockIdx.x & 7;
  const int idx = blockIdx.x >> 3;       // 0..63
  const int bh = xcd * 4 + (idx >> 4);   // 4 heads per XCD
  const int qc = idx & 15;               // 128-row chunk
  const int h = bh & (NH - 1);
  const int b = bh >> 4;
  const int lane = threadIdx.x & 63;
  const int wave = threadIdx.x >> 6;     // 0..7
  const int g = lane >> 4;
  const int c16 = lane & 15;
  const int qrow = qc * 128 + wave * 16 + c16;  // this wave's 16 q-rows

  // 4 buffers x (8 K-frags | 8 V-frags) x 1KB = 64 KB (grid caps at 2 blocks/CU)
  __shared__ __align__(16) bf16 lds_kv[4][16 * 512];

  // Q projection in-register; scale folded pre-cvt.
  const float* xq = Qin + ((size_t)b * S_LEN + qrow) * E_DIM + h * HD;
  bf16x8 xqf[2];
#pragma unroll
  for (int c = 0; c < 2; ++c) xqf[c] = load_cvt_frag(xq + 32 * c + 4 * g);
  f32x4 qt[4];
#pragma unroll
  for (int t = 0; t < 4; ++t) {
    const float* wr = Wq + (16 * t + c16) * HD + 4 * g;
    f32x4 acc = {0.f, 0.f, 0.f, 0.f};
    acc = MFMA(load_cvt_frag(wr), xqf[0], acc);
    acc = MFMA(load_cvt_frag(wr + 32), xqf[1], acc);
#pragma unroll
    for (int r = 0; r < 4; ++r) acc[r] = (acc[r] + bq[16 * t + 4 * g + r]) * SCALE_L2E;
    qt[t] = acc;
  }
  bf16x8 qfrag0 = cvt8(qt[0], qt[1]);
  bf16x8 qfrag1 = cvt8(qt[2], qt[3]);

  bf16x8 ones;
#pragma unroll
  for (int i = 0; i < 8; ++i) ones[i] = (bf16)1.0f;

  const bf16* ktile = KpF + ((size_t)bh * 32) * 4096;  // + t*4096 + f*512
  const bf16* vtile = VpF + ((size_t)bh * 32) * 4096;
  const u64* mrowT = mbits + qrow;                     // + t*S_LEN

  f32x4 o[4] = {};
  f32x4 o5 = {};

  // wave w stages K frag w and V frag w: 2 gload_lds per tile per wave
#define STAGE(BUF, T)                                                              \
  {                                                                                \
    const bf16* ks_ = ktile + (size_t)(T) * 4096 + wave * 512 + lane * 8;          \
    const bf16* vs_ = vtile + (size_t)(T) * 4096 + wave * 512 + lane * 8;          \
    __builtin_amdgcn_global_load_lds(                                              \
        (const __attribute__((address_space(1))) u32*)ks_,                         \
        (__attribute__((address_space(3))) u32*)((BUF) + wave * 512), 16, 0, 0);   \
    __builtin_amdgcn_global_load_lds(                                              \
        (const __attribute__((address_space(1))) u32*)vs_,                         \
        (__attribute__((address_space(3))) u32*)((BUF) + 4096 + wave * 512), 16, 0, 0); \
  }

// COMPUTE: R16's per-tile body (kf<-LDS, QK, mask+exp2, cvt, PV)
#define COMPUTE(BUF, MW)                                                          \
  {                                                                               \
    bf16x8 kf[8], vfr[8];                                                         \
    _Pragma("unroll") for (int f = 0; f < 8; ++f)                                 \
        kf[f] = *(const bf16x8*)((BUF) + f * 512 + lane * 8);                     \
    f32x4 st[4];                                                                  \
    __builtin_amdgcn_s_setprio(1);                                                \
    _Pragma("unroll") for (int ks = 0; ks < 4; ++ks) {                            \
      f32x4 acc = {0.f, 0.f, 0.f, 0.f};                                           \
      acc = MFMA(kf[2 * ks], qfrag0, acc);                                        \
      acc = MFMA(kf[2 * ks + 1], qfrag1, acc);                                    \
      st[ks] = acc;                                                               \
    }                                                                             \
    __builtin_amdgcn_s_setprio(0);                                                \
    _Pragma("unroll") for (int f = 0; f < 8; ++f)                                 \
        vfr[f] = *(const bf16x8*)((BUF) + 4096 + f * 512 + lane * 8);             \
    const u64 mws = (MW) >> (4 * g);                                              \
    const u32 mlo = (u32)mws;                                                     \
    const u32 mhi = (u32)(mws >> 32);                                             \
    _Pragma("unroll") for (int ks = 0; ks < 4; ++ks) {                            \
      const u32 mword = (ks < 2) ? mlo : mhi;                                     \
      const int base = (ks & 1) * 16;                                             \
      _Pragma("unroll") for (int r = 0; r < 4; ++r) {                             \
        const float p = __builtin_amdgcn_exp2f(st[ks][r]);                        \
        const int keep = __builtin_amdgcn_sbfe(mword, base + r, 1);               \
        st[ks][r] = __uint_as_float(__float_as_uint(p) & (u32)keep);              \
      }                                                                           \
    }                                                                             \
    const bf16x8 pfrag0 = cvt8(st[0], st[1]);                                     \
    const bf16x8 pfrag1 = cvt8(st[2], st[3]);                                     \
    __builtin_amdgcn_s_setprio(1);                                                \
    _Pragma("unroll") for (int t = 0; t < 4; ++t) {                               \
      o[t] = MFMA(vfr[2 * t], pfrag0, o[t]);                                      \
      o[t] = MFMA(vfr[2 * t + 1], pfrag1, o[t]);                                  \
    }                                                                             \
    o5 = MFMA(ones, pfrag0, o5);                                                  \
    o5 = MFMA(ones, pfrag1, o5);                                                  \
    __builtin_amdgcn_s_setprio(0);                                                \
  }

  bf16* const B0 = &lds_kv[0][0];
  bf16* const B1 = &lds_kv[1][0];
  bf16* const B2 = &lds_kv[2][0];
  bf16* const B3 = &lds_kv[3][0];

  u64 mA, mB, mC, mD;

  // prologue: stage tiles 0,1; masks 0,1; retire the 4 stage loads
  STAGE(B0, 0)
  STAGE(B1, 1)
  mA = mrowT[0];
  mB = mrowT[S_LEN];
  asm volatile("s_waitcnt vmcnt(2)" ::: "memory");
  asm volatile("s_barrier" ::: "memory");

  // PHASE: [stage t+2 -> SA, t+3 -> SB][masks t+2,t+3][compute t][compute t+1][vmcnt(2)][barrier]
#define PHASE(BA, BB, SA, SB, MC0, MC1, MN0, MN1, T)                              \
  {                                                                               \
    const bool m2_ = (T) + 2 < NT;                                                \
    const bool m3_ = (T) + 3 < NT;                                                \
    if (m2_) STAGE(SA, (T) + 2)                                                   \
    if (m3_) STAGE(SB, (T) + 3)                                                   \
    if (m2_) MN0 = mrowT[(size_t)((T) + 2) * S_LEN];                              \
    if (m3_) MN1 = mrowT[(size_t)((T) + 3) * S_LEN];                              \
    COMPUTE(BA, MC0)                                                              \
    COMPUTE(BB, MC1)                                                              \
    if (m2_) asm volatile("s_waitcnt vmcnt(2)" ::: "memory");                     \
    else     asm volatile("s_waitcnt vmcnt(0)" ::: "memory");                     \
    asm volatile("s_barrier" ::: "memory");                                       \
  }

  for (int t = 0; t < NT; t += 4) {
    PHASE(B0, B1, B2, B3, mA, mB, mC, mD, t)
    PHASE(B2, B3, B0, B1, mC, mD, mA, mB, t + 2)
  }
#undef PHASE
#undef COMPUTE
#undef STAGE

  const float inv = 1.0f / o5[0];
  float* orow = out + ((size_t)b * S_LEN + qrow) * E_DIM + h * HD;
#pragma unroll
  for (int t = 0; t < 4; ++t) {
    f32x4 v;
#pragma unroll
    for (int r = 0; r < 4; ++r) v[r] = o[t][r] * inv;
    *(f32x4*)(orow + 16 * t + 4 * g) = v;
  }
}

extern "C" void kernel_launch(void* const* d_in, const int* in_sizes, int n_in,
                              void* d_out, int out_size, void* d_ws, size_t ws_size,
                              hipStream_t stream) {
  const float* Q = (const float*)d_in[0];
  const float* K = (const float*)d_in[1];
  const float* V = (const float*)d_in[2];
  const int* mask = (const int*)d_in[3];
  const float* Wq = (const float*)d_in[4];
  const float* bq = (const float*)d_in[5];
  const float* Wk = (const float*)d_in[6];
  const float* bk = (const float*)d_in[7];
  const float* Wv = (const float*)d_in[8];
  const float* bv = (const float*)d_in[9];
  float* out = (float*)d_out;

  char* ws = (char*)d_ws;
  const size_t proj_bytes = (size_t)2 * NH * S_LEN * HD * 2;  // 8 MB each (B=2)
  bf16* KpF = (bf16*)ws;
  bf16* VpF = (bf16*)(ws + proj_bytes);
  u64* mbits = (u64*)(ws + 2 * proj_bytes);      // 512 KB

  kvproj_k<<<2 * NH * (S_LEN / 64), 256, 0, stream>>>(K, V, Wk, bk, Wv, bv, mask,
                                                      KpF, VpF, mbits);
  // 512 blocks x 512 threads: 8 waves x 16 q-rows = 128 q-rows per block
  attn_k<<<2 * NH * (S_LEN / 128), 512, 0, stream>>>(Q, Wq, bq, KpF, VpF, mbits, out);
}